// Round 6
// baseline (220.193 us; speedup 1.0000x reference)
//
#include <hip/hip_runtime.h>
#include <hip/hip_bf16.h>

#define B_DIM 64
#define T_DIM 512
#define H_DIM 1024

typedef __attribute__((ext_vector_type(8))) __bf16 bf16x8;
typedef __attribute__((ext_vector_type(8))) unsigned short u16x8;
typedef __attribute__((ext_vector_type(16))) float f32x16;

// ws layout (bytes)
#define AQ_OFF  0UL               // A' frag-major: 64*512*1024*2 = 67108864
#define BQ_OFF  67108864UL        // B' frag-major: 1024*1024*2   =  2097152
#define DEC_OFF 69206016UL        // 64*1024*4     =   262144
#define PART_OFF 69468160UL       // 32768*8*4     =  1048576
#define AT_OFF  70516736UL        // 32768*4       =   131072
// total 70647808 bytes

__device__ __forceinline__ unsigned short f2bf(float x) {
  unsigned u = __float_as_uint(x);
  unsigned r = (u + 0x7FFFu + ((u >> 16) & 1u)) >> 16;  // RNE
  return (unsigned short)r;
}
__device__ __forceinline__ float bf2f(unsigned short u) {
  return __uint_as_float(((unsigned)u) << 16);
}

__device__ __forceinline__ void gload_lds16(const void* g, void* l) {
  __builtin_amdgcn_global_load_lds(
      (const __attribute__((address_space(1))) void*)g,
      (__attribute__((address_space(3))) void*)l, 16, 0, 0);
}

// Fragment-major layout (verified by R4 pass):
// X'[(row>>5)][(k>>4)] is a 1KB fragment; lane l holds X[row = l&31][k = (l>>5)*8 + j]
// element offset = ((row>>5)*64 + (k>>4))*512 + (l)*8 ... (l = (k>>3 &1)*32 + row&31)

// K1: prep — prev_s -> A' (+ fp32 concat copy), W_prev -> B', s_t -> out tail.
__global__ void prep_ws(const float* __restrict__ prev,
                        const float* __restrict__ st,
                        const float* __restrict__ Wp,
                        float* __restrict__ out,
                        unsigned short* __restrict__ Aq,
                        unsigned short* __restrict__ Bq) {
  int wid = blockIdx.x * 4 + (threadIdx.x >> 6);
  int lane = threadIdx.x & 63;
  int hi = lane >> 5, r = lane & 31;
  if (wid < 8192) {
    int mt = wid >> 3;
    int kg0 = (wid & 7) * 8;
    int m = mt * 32 + r;
    int b = m >> 9, t = m & 511;
    const float* src = prev + (size_t)m * 1024;
    float* outp = out + 65536 + (size_t)b * 525312 + (size_t)t * 1024;
    #pragma unroll
    for (int kg = kg0; kg < kg0 + 8; kg++) {
      int k0 = kg * 16 + hi * 8;
      float4 f0 = *(const float4*)(src + k0);
      float4 f1 = *(const float4*)(src + k0 + 4);
      *(float4*)(outp + k0) = f0;
      *(float4*)(outp + k0 + 4) = f1;
      u16x8 u;
      u[0] = f2bf(f0.x); u[1] = f2bf(f0.y); u[2] = f2bf(f0.z); u[3] = f2bf(f0.w);
      u[4] = f2bf(f1.x); u[5] = f2bf(f1.y); u[6] = f2bf(f1.z); u[7] = f2bf(f1.w);
      *(u16x8*)(Aq + ((size_t)mt * 64 + kg) * 512 + (size_t)lane * 8) = u;
    }
  } else if (wid < 8448) {
    int rel = wid - 8192;
    int nt = rel >> 3;
    int kg0 = (rel & 7) * 8;
    int n = nt * 32 + r;
    const float* src = Wp + (size_t)n * 1024;
    #pragma unroll
    for (int kg = kg0; kg < kg0 + 8; kg++) {
      int k0 = kg * 16 + hi * 8;
      float4 f0 = *(const float4*)(src + k0);
      float4 f1 = *(const float4*)(src + k0 + 4);
      u16x8 u;
      u[0] = f2bf(f0.x); u[1] = f2bf(f0.y); u[2] = f2bf(f0.z); u[3] = f2bf(f0.w);
      u[4] = f2bf(f1.x); u[5] = f2bf(f1.y); u[6] = f2bf(f1.z); u[7] = f2bf(f1.w);
      *(u16x8*)(Bq + ((size_t)nt * 64 + kg) * 512 + (size_t)lane * 8) = u;
    }
  } else if (wid < 8512) {
    int b = wid - 8448;
    const float4* s4 = (const float4*)st;
    float4* o4 = (float4*)(out + 65536 + (size_t)b * 525312 + 524288);
    #pragma unroll
    for (int i = 0; i < 4; i++)
      o4[i * 64 + lane] = s4[(size_t)b * 256 + i * 64 + lane];
  }
}

// K2: dec_fea[b][o] = sum_h s_t[b][h]*W_s[o][h] + b_s[o]
__global__ void dec_kernel(const float* __restrict__ st,
                           const float* __restrict__ Ws,
                           const float* __restrict__ bs,
                           float* __restrict__ dec) {
  int tid = threadIdx.x;
  int lane = tid & 63, w = tid >> 6;
  int o = blockIdx.x * 4 + w;
  const float4* wrow = (const float4*)(Ws + (size_t)o * H_DIM);
  float4 w0 = wrow[lane], w1 = wrow[64 + lane], w2 = wrow[128 + lane], w3 = wrow[192 + lane];
  const float4* st4 = (const float4*)st;
  float bias = bs[o];
  #pragma unroll 8
  for (int b = 0; b < B_DIM; b++) {
    const float4* s = st4 + (size_t)b * 256;
    float4 s0 = s[lane], s1 = s[64 + lane], s2 = s[128 + lane], s3 = s[192 + lane];
    float p = w0.x * s0.x + w0.y * s0.y + w0.z * s0.z + w0.w * s0.w
            + w1.x * s1.x + w1.y * s1.y + w1.z * s1.z + w1.w * s1.w
            + w2.x * s2.x + w2.y * s2.y + w2.z * s2.z + w2.w * s2.w
            + w3.x * s3.x + w3.y * s3.y + w3.z * s3.z + w3.w * s3.w;
    p += __shfl_xor(p, 1);  p += __shfl_xor(p, 2);
    p += __shfl_xor(p, 4);  p += __shfl_xor(p, 8);
    p += __shfl_xor(p, 16); p += __shfl_xor(p, 32);
    if (lane == 0) dec[(size_t)b * H_DIM + o] = p + bias;
  }
}

// K3: split-path score GEMM. 128x128 block tile, 4 waves (2x2), 64x64/wave.
// A: frag-major -> LDS (quad-buffered, depth-3 prefetch, linear gload_lds).
// B: frag-major -> registers direct from L2 (ping-pong, depth-2).
// One s_barrier per K32-step; counted vmcnt; fused tanh-dot-v epilogue.
__global__ __launch_bounds__(256, 2) void score_gemm(
    const unsigned short* __restrict__ Aq,
    const unsigned short* __restrict__ Bq,
    const float* __restrict__ dec,
    const float* __restrict__ v,
    float* __restrict__ part)
{
  __shared__ __align__(16) unsigned short ldsA[4][4096];  // 4 bufs x 8KB

  int orig = blockIdx.x;                       // 2048 blocks
  int swz = (orig & 7) * 256 + (orig >> 3);    // bijective XCD swizzle
  int bm = swz >> 3, bn = swz & 7;

  int tid = threadIdx.x;
  int lane = tid & 63, w = tid >> 6;
  int wm = w >> 1, wn = w & 1;
  size_t m0 = (size_t)bm * 128;

  // A staging: 512 chunks of 16B per K32-step; chunk c: frag f=c>>6, inner=c&63
  int f0 = tid >> 6;             // chunks c0 = tid
  int f1 = 4 + (tid >> 6);       // chunks c1 = tid + 256
  const unsigned short* gA0 =
      Aq + (((size_t)bm * 4 + (f0 >> 1)) * 64 + (f0 & 1)) * 512 + (size_t)(tid & 63) * 8;
  const unsigned short* gA1 =
      Aq + (((size_t)bm * 4 + (f1 >> 1)) * 64 + (f1 & 1)) * 512 + (size_t)(tid & 63) * 8;

  // B frags: this wave's 64 cols = nt bn*4+wn*2 .. +1
  const unsigned short* gB =
      Bq + (((size_t)bn * 4 + wn * 2) * 64) * 512 + (size_t)lane * 8;

  f32x16 acc[2][2];
  #pragma unroll
  for (int i = 0; i < 2; i++)
    #pragma unroll
    for (int j = 0; j < 2; j++)
      #pragma unroll
      for (int e = 0; e < 16; e++) acc[i][j][e] = 0.f;

  bf16x8 Breg[2][4];

#define STAGE(buf, t) do { \
    gload_lds16(gA0 + (size_t)(t) * 1024, &ldsA[(buf)][tid * 8]); \
    gload_lds16(gA1 + (size_t)(t) * 1024, &ldsA[(buf)][(tid + 256) * 8]); \
  } while (0)

#define LOADB(slot, t) do { \
    Breg[slot][0] = *(const bf16x8*)(gB + (size_t)(2 * (t)) * 512); \
    Breg[slot][1] = *(const bf16x8*)(gB + (size_t)(2 * (t) + 1) * 512); \
    Breg[slot][2] = *(const bf16x8*)(gB + 32768 + (size_t)(2 * (t)) * 512); \
    Breg[slot][3] = *(const bf16x8*)(gB + 32768 + (size_t)(2 * (t) + 1) * 512); \
  } while (0)

  // prologue — queue order matches steady state: A(t),A(t+1),B(t),A(t+2),B(t+1)
  STAGE(0, 0);
  STAGE(1, 1);
  LOADB(0, 0);
  STAGE(2, 2);
  LOADB(1, 1);

  #pragma unroll
  for (int t = 0; t < 32; t++) {
    // ledger: steady outstanding = A(t)2,A(t+1)2,B(t)4,A(t+2)2,B(t+1)4 = 14
    // drain A(t)+B(t) -> leave 6 (robust to stage/loadB intra-body order)
    if (t < 30)       asm volatile("s_waitcnt vmcnt(6)" ::: "memory");
    else if (t == 30) asm volatile("s_waitcnt vmcnt(4)" ::: "memory");
    else              asm volatile("s_waitcnt vmcnt(0)" ::: "memory");
    __builtin_amdgcn_s_barrier();
    asm volatile("" ::: "memory");

    bf16x8 a[2][2];
    #pragma unroll
    for (int mf = 0; mf < 2; mf++)
      #pragma unroll
      for (int kk = 0; kk < 2; kk++)
        a[mf][kk] = *(const bf16x8*)&ldsA[t & 3][((wm * 2 + mf) * 2 + kk) * 512 + lane * 8];

    if (t + 3 < 32) STAGE((t + 3) & 3, t + 3);

    __builtin_amdgcn_s_setprio(1);
    #pragma unroll
    for (int mf = 0; mf < 2; mf++)
      #pragma unroll
      for (int nf = 0; nf < 2; nf++)
        #pragma unroll
        for (int kk = 0; kk < 2; kk++)
          acc[mf][nf] = __builtin_amdgcn_mfma_f32_32x32x16_bf16(
              a[mf][kk], Breg[t & 1][nf * 2 + kk], acc[mf][nf], 0, 0, 0);
    __builtin_amdgcn_s_setprio(0);

    if (t + 2 < 32) LOADB(t & 1, t + 2);
  }
#undef STAGE
#undef LOADB

  // epilogue: tanh + dot v over this wave's 64 cols; wn-pair reduce via LDS.
  // C layout (32x32): col = lane&31, row = (r&3) + 8*(r>>2) + 4*(lane>>5)
  int b = (int)(m0 >> 9);
  int cl = lane & 31, hi = lane >> 5;
  int n0 = bn * 128;
  float dv[2], vv[2];
  #pragma unroll
  for (int nf = 0; nf < 2; nf++) {
    int col = n0 + wn * 64 + nf * 32 + cl;
    dv[nf] = dec[(size_t)b * H_DIM + col];
    vv[nf] = v[col];
  }
  float* epi = (float*)&ldsA[0][0];  // [128 rows][2 wn] floats = 1KB
  #pragma unroll
  for (int mf = 0; mf < 2; mf++) {
    #pragma unroll
    for (int r = 0; r < 16; r++) {
      float s = 0.f;
      #pragma unroll
      for (int nf = 0; nf < 2; nf++) {
        float x = acc[mf][nf][r] + dv[nf];
        x = fminf(fmaxf(x, -15.f), 15.f);
        float e = __expf(2.f * x);
        s += vv[nf] * (e - 1.f) * __builtin_amdgcn_rcpf(e + 1.f);
      }
      s += __shfl_xor(s, 1); s += __shfl_xor(s, 2);
      s += __shfl_xor(s, 4); s += __shfl_xor(s, 8); s += __shfl_xor(s, 16);
      if (cl == 0) {
        int row = wm * 64 + mf * 32 + (r & 3) + 8 * (r >> 2) + 4 * hi;
        epi[row * 2 + wn] = s;
      }
    }
  }
  __syncthreads();
  if (tid < 128) {
    part[(m0 + tid) * 8 + bn] = epi[tid * 2] + epi[tid * 2 + 1];
  }
}

// K4: softmax over T per batch row (8 partials per row)
__global__ void softmax_kernel(const float* __restrict__ part, float* __restrict__ at) {
  int b = blockIdx.x, tid = threadIdx.x;
  __shared__ float sc[512];
  __shared__ float red[8];
  #pragma unroll
  for (int rep = 0; rep < 2; rep++) {
    int t = rep * 256 + tid;
    const float* p = part + ((size_t)b * 512 + t) * 8;
    sc[t] = p[0] + p[1] + p[2] + p[3] + p[4] + p[5] + p[6] + p[7];
  }
  __syncthreads();
  float m = fmaxf(sc[tid], sc[tid + 256]);
  for (int d = 1; d < 64; d <<= 1) m = fmaxf(m, __shfl_xor(m, d));
  if ((tid & 63) == 0) red[tid >> 6] = m;
  __syncthreads();
  m = fmaxf(fmaxf(red[0], red[1]), fmaxf(red[2], red[3]));
  float e0 = __expf(sc[tid] - m), e1 = __expf(sc[tid + 256] - m);
  float s = e0 + e1;
  for (int d = 1; d < 64; d <<= 1) s += __shfl_xor(s, d);
  if ((tid & 63) == 0) red[4 + (tid >> 6)] = s;
  __syncthreads();
  s = red[4] + red[5] + red[6] + red[7];
  float inv = 1.f / s;
  at[(size_t)b * 512 + tid] = e0 * inv;
  at[(size_t)b * 512 + tid + 256] = e1 * inv;
}

// K5: ct_d[b][h] = sum_t at[b][t]*prev[b][t][h], reading fragment-major A'.
// One wave owns (b, kg): 16 h-values, full t-reduction in-wave. No atomics.
__global__ void ctd_ws(const unsigned short* __restrict__ Aq,
                       const float* __restrict__ at, float* __restrict__ out) {
  int wid = blockIdx.x * 4 + (threadIdx.x >> 6);  // 4096 = 64 b x 64 kg
  int lane = threadIdx.x & 63;
  int b = wid >> 6, kg = wid & 63;
  int hi = lane >> 5, r = lane & 31;
  float a8[8] = {0.f, 0.f, 0.f, 0.f, 0.f, 0.f, 0.f, 0.f};
  const unsigned short* base = Aq + ((size_t)b * 16 * 64 + kg) * 512 + (size_t)lane * 8;
  const float* atb = at + (size_t)b * 512 + r;
  #pragma unroll
  for (int mt = 0; mt < 16; mt++) {
    float a = atb[mt * 32];
    u16x8 val = *(const u16x8*)(base + (size_t)mt * 32768);
    #pragma unroll
    for (int j = 0; j < 8; j++) a8[j] += a * bf2f(val[j]);
  }
  #pragma unroll
  for (int d = 1; d < 32; d <<= 1)
    #pragma unroll
    for (int j = 0; j < 8; j++) a8[j] += __shfl_xor(a8[j], d);
  if (r == 0) {
    #pragma unroll
    for (int j = 0; j < 8; j++)
      out[(size_t)b * H_DIM + kg * 16 + hi * 8 + j] = a8[j];
  }
}

extern "C" void kernel_launch(void* const* d_in, const int* in_sizes, int n_in,
                              void* d_out, int out_size, void* d_ws, size_t ws_size,
                              hipStream_t stream) {
  (void)in_sizes; (void)n_in; (void)out_size; (void)ws_size;
  const float* s_t    = (const float*)d_in[0];
  const float* prev_s = (const float*)d_in[1];
  const float* W_prev = (const float*)d_in[2];
  const float* W_s    = (const float*)d_in[3];
  const float* b_s    = (const float*)d_in[4];
  const float* v      = (const float*)d_in[5];
  float* out = (float*)d_out;
  char* ws = (char*)d_ws;

  unsigned short* Aq = (unsigned short*)(ws + AQ_OFF);
  unsigned short* Bq = (unsigned short*)(ws + BQ_OFF);
  float* dec  = (float*)(ws + DEC_OFF);
  float* part = (float*)(ws + PART_OFF);
  float* at   = (float*)(ws + AT_OFF);

  prep_ws<<<2128, 256, 0, stream>>>(prev_s, s_t, W_prev, out, Aq, Bq);
  dec_kernel<<<256, 256, 0, stream>>>(s_t, W_s, b_s, dec);
  score_gemm<<<2048, 256, 0, stream>>>(Aq, Bq, dec, v, part);
  softmax_kernel<<<64, 256, 0, stream>>>(part, at);
  ctd_ws<<<1024, 256, 0, stream>>>(Aq, at, out);
}

// Round 7
// 179.272 us; speedup vs baseline: 1.2283x; 1.2283x over previous
//
#include <hip/hip_runtime.h>
#include <hip/hip_bf16.h>

#define B_DIM 64
#define T_DIM 512
#define H_DIM 1024

typedef __attribute__((ext_vector_type(4))) float f32x4;

// ws layout (bytes)
#define AQ8_OFF  0UL              // A' fp8 frag-major: 32768*1024 = 33554432
#define BQ8_OFF  33554432UL       // B' fp8 frag-major: 1024*1024  =  1048576
#define DEC_OFF  34603008UL       // 64*1024*4  =  262144
#define PART_OFF 34865152UL       // 32768*8*4  = 1048576
#define AT_OFF   35913728UL       // 32768*4    =  131072
// total 36044800 bytes

// ---- OCP e4m3fn encode (RNE, satfinite) / decode — self-consistent pair ----
__device__ __forceinline__ unsigned char f2e4m3(float x) {
  float a = fabsf(x);
  unsigned s = (__float_as_uint(x) >> 31) << 7;
  a = fminf(a, 448.0f);
  unsigned char r;
  if (a < 0.015625f) {                       // subnormal: m * 2^-9
    int mi = (int)rintf(a * 512.0f);         // 0..8
    r = (unsigned char)mi;                   // mi==8 -> 0x08 == 2^-6 (e=1,m=0)
  } else {
    int ep = (int)(__float_as_uint(a) >> 23) - 127;          // -6..8
    float scale = __uint_as_float((unsigned)(130 - ep) << 23); // 2^(3-ep)
    int mi = (int)rintf(a * scale);          // 8..16
    if (mi == 16) { mi = 8; ep++; }
    r = (unsigned char)(((ep + 7) << 3) | (mi - 8));
  }
  return (unsigned char)(r | s);
}
__device__ __forceinline__ float e4m3f(unsigned char v) {
  unsigned e = (v >> 3) & 15u, m = v & 7u;
  float mag = (e == 0) ? (float)m * 0.001953125f
                       : (float)(8 + m) * __uint_as_float((e + 117u) << 23);
  return (v & 0x80u) ? -mag : mag;
}

__device__ __forceinline__ void gload_lds16(const void* g, void* l) {
  __builtin_amdgcn_global_load_lds(
      (const __attribute__((address_space(1))) void*)g,
      (__attribute__((address_space(3))) void*)l, 16, 0, 0);
}

// Fragment-major fp8 layout (16x16x32 MFMA frags):
// frag(mt,kt) = 512B at ((mt*32)+kt)*512; lane l holds X[row=mt*16+(l&15)]
// [k = kt*32 + (l>>4)*8 + j], j=0..7.  (bf16 analog verified in R2/R4.)

// K1: prep — prev_s -> fp32 concat copy + fp8*4 A-frags; W_prev -> fp8*16
// B-frags; s_t -> concat tail.
__global__ void prep_ws(const float* __restrict__ prev,
                        const float* __restrict__ st,
                        const float* __restrict__ Wp,
                        float* __restrict__ out,
                        unsigned char* __restrict__ Aq,
                        unsigned char* __restrict__ Bq) {
  int wid = blockIdx.x * 4 + (threadIdx.x >> 6);
  int lane = threadIdx.x & 63;
  int lc = lane & 15, lr = lane >> 4;
  if (wid < 8192) {                       // A: 2048 mt x 4 kt-groups
    int mt = wid >> 2;
    int kt0 = (wid & 3) * 8;
    int m = mt * 16 + lc;
    int b = m >> 9, t = m & 511;
    const float* src = prev + (size_t)m * 1024;
    float* outp = out + 65536 + (size_t)b * 525312 + (size_t)t * 1024;
    #pragma unroll
    for (int kt = kt0; kt < kt0 + 8; kt++) {
      int k0 = kt * 32 + lr * 8;
      float4 f0 = *(const float4*)(src + k0);
      float4 f1 = *(const float4*)(src + k0 + 4);
      *(float4*)(outp + k0) = f0;
      *(float4*)(outp + k0 + 4) = f1;
      unsigned char q[8];
      q[0] = f2e4m3(f0.x * 4.f); q[1] = f2e4m3(f0.y * 4.f);
      q[2] = f2e4m3(f0.z * 4.f); q[3] = f2e4m3(f0.w * 4.f);
      q[4] = f2e4m3(f1.x * 4.f); q[5] = f2e4m3(f1.y * 4.f);
      q[6] = f2e4m3(f1.z * 4.f); q[7] = f2e4m3(f1.w * 4.f);
      *(uint2*)(Aq + ((size_t)mt * 32 + kt) * 512 + (size_t)lane * 8) = *(uint2*)q;
    }
  } else if (wid < 8448) {                // B: 64 nt x 4 kt-groups
    int rel = wid - 8192;
    int nt = rel >> 2;
    int kt0 = (rel & 3) * 8;
    int n = nt * 16 + lc;
    const float* src = Wp + (size_t)n * 1024;
    #pragma unroll
    for (int kt = kt0; kt < kt0 + 8; kt++) {
      int k0 = kt * 32 + lr * 8;
      float4 f0 = *(const float4*)(src + k0);
      float4 f1 = *(const float4*)(src + k0 + 4);
      unsigned char q[8];
      q[0] = f2e4m3(f0.x * 16.f); q[1] = f2e4m3(f0.y * 16.f);
      q[2] = f2e4m3(f0.z * 16.f); q[3] = f2e4m3(f0.w * 16.f);
      q[4] = f2e4m3(f1.x * 16.f); q[5] = f2e4m3(f1.y * 16.f);
      q[6] = f2e4m3(f1.z * 16.f); q[7] = f2e4m3(f1.w * 16.f);
      *(uint2*)(Bq + ((size_t)nt * 32 + kt) * 512 + (size_t)lane * 8) = *(uint2*)q;
    }
  } else if (wid < 8512) {                // s_t -> concat tail rows
    int b = wid - 8448;
    const float4* s4 = (const float4*)st;
    float4* o4 = (float4*)(out + 65536 + (size_t)b * 525312 + 524288);
    #pragma unroll
    for (int i = 0; i < 4; i++)
      o4[i * 64 + lane] = s4[(size_t)b * 256 + i * 64 + lane];
  }
}

// K2: dec_fea[b][o] = sum_h s_t[b][h]*W_s[o][h] + b_s[o]
__global__ void dec_kernel(const float* __restrict__ st,
                           const float* __restrict__ Ws,
                           const float* __restrict__ bs,
                           float* __restrict__ dec) {
  int tid = threadIdx.x;
  int lane = tid & 63, w = tid >> 6;
  int o = blockIdx.x * 4 + w;
  const float4* wrow = (const float4*)(Ws + (size_t)o * H_DIM);
  float4 w0 = wrow[lane], w1 = wrow[64 + lane], w2 = wrow[128 + lane], w3 = wrow[192 + lane];
  const float4* st4 = (const float4*)st;
  float bias = bs[o];
  #pragma unroll 8
  for (int b = 0; b < B_DIM; b++) {
    const float4* s = st4 + (size_t)b * 256;
    float4 s0 = s[lane], s1 = s[64 + lane], s2 = s[128 + lane], s3 = s[192 + lane];
    float p = w0.x * s0.x + w0.y * s0.y + w0.z * s0.z + w0.w * s0.w
            + w1.x * s1.x + w1.y * s1.y + w1.z * s1.z + w1.w * s1.w
            + w2.x * s2.x + w2.y * s2.y + w2.z * s2.z + w2.w * s2.w
            + w3.x * s3.x + w3.y * s3.y + w3.z * s3.z + w3.w * s3.w;
    p += __shfl_xor(p, 1);  p += __shfl_xor(p, 2);
    p += __shfl_xor(p, 4);  p += __shfl_xor(p, 8);
    p += __shfl_xor(p, 16); p += __shfl_xor(p, 32);
    if (lane == 0) dec[(size_t)b * H_DIM + o] = p + bias;
  }
}

// K3: fp8 score GEMM. 128x128 block, 2x2 waves of 64x64, BK=64,
// fragment-major LDS (linear stage, conflict-free ds_read_b64),
// R5's raw-barrier + counted-vmcnt(4) scaffolding. acc = 64*et.
__global__ __launch_bounds__(256, 3) void score_gemm(
    const unsigned char* __restrict__ Aq,
    const unsigned char* __restrict__ Bq,
    const float* __restrict__ dec,
    const float* __restrict__ v,
    float* __restrict__ part)
{
  __shared__ __align__(16) unsigned char ldsA[2][8192];
  __shared__ __align__(16) unsigned char ldsB[2][8192];

  int orig = blockIdx.x;                       // 2048 blocks
  int swz = (orig & 7) * 256 + (orig >> 3);    // bijective XCD swizzle
  int bm = swz >> 3, bn = swz & 7;

  int tid = threadIdx.x;
  int lane = tid & 63, w = tid >> 6;
  int wm = w >> 1, wn = w & 1;                 // 2x2 waves, 64x64 each
  size_t m0 = (size_t)bm * 128;

  f32x4 acc[4][4];
  #pragma unroll
  for (int i = 0; i < 4; i++)
    #pragma unroll
    for (int j = 0; j < 4; j++) {
      f32x4 z; z.x = 0.f; z.y = 0.f; z.z = 0.f; z.w = 0.f;
      acc[i][j] = z;
    }

  // staging: per step 512 chunks/matrix; thread owns chunks tid, tid+256.
  // chunk c: frag f=c>>5 (mt=f>>1, ktl=f&1), 16B piece cif=c&31.
  int fA = tid >> 5, cif = tid & 31;
  const unsigned char* aSrc0 =
      Aq + ((size_t)(bm * 8 + (fA >> 1)) * 32 + (fA & 1)) * 512 + (size_t)cif * 16;
  const unsigned char* aSrc1 =
      Aq + ((size_t)(bm * 8 + (fA >> 1) + 4) * 32 + (fA & 1)) * 512 + (size_t)cif * 16;
  const unsigned char* bSrc0 =
      Bq + ((size_t)(bn * 8 + (fA >> 1)) * 32 + (fA & 1)) * 512 + (size_t)cif * 16;
  const unsigned char* bSrc1 =
      Bq + ((size_t)(bn * 8 + (fA >> 1) + 4) * 32 + (fA & 1)) * 512 + (size_t)cif * 16;

#define STAGE(buf, t) do { \
    size_t ko = (size_t)(t) * 1024; \
    gload_lds16(aSrc0 + ko, &ldsA[(buf)][tid * 16]); \
    gload_lds16(aSrc1 + ko, &ldsA[(buf)][tid * 16 + 4096]); \
    gload_lds16(bSrc0 + ko, &ldsB[(buf)][tid * 16]); \
    gload_lds16(bSrc1 + ko, &ldsB[(buf)][tid * 16 + 4096]); \
  } while (0)

  // prologue: stage tile 0 (4 loads/thread in flight)
  STAGE(0, 0);

  #pragma unroll 2
  for (int t = 0; t < 16; t++) {
    int cur = t & 1, nxt = cur ^ 1;
    if (t < 15) {
      STAGE(nxt, t + 1);
      asm volatile("s_waitcnt vmcnt(4)" ::: "memory");  // cur landed; nxt in flight
    } else {
      asm volatile("s_waitcnt vmcnt(0)" ::: "memory");
    }
    __builtin_amdgcn_s_barrier();
    asm volatile("" ::: "memory");

    const unsigned char* Ac = &ldsA[cur][0];
    const unsigned char* Bc = &ldsB[cur][0];
    long av[4][2], bv[4][2];
    #pragma unroll
    for (int mf = 0; mf < 4; mf++)
      #pragma unroll
      for (int kk = 0; kk < 2; kk++)
        av[mf][kk] = *(const long*)(Ac + ((wm * 4 + mf) * 2 + kk) * 512 + lane * 8);
    #pragma unroll
    for (int nf = 0; nf < 4; nf++)
      #pragma unroll
      for (int kk = 0; kk < 2; kk++)
        bv[nf][kk] = *(const long*)(Bc + ((wn * 4 + nf) * 2 + kk) * 512 + lane * 8);

    __builtin_amdgcn_s_setprio(1);
    #pragma unroll
    for (int kk = 0; kk < 2; kk++)
      #pragma unroll
      for (int mf = 0; mf < 4; mf++)
        #pragma unroll
        for (int nf = 0; nf < 4; nf++)
          acc[mf][nf] = __builtin_amdgcn_mfma_f32_16x16x32_fp8_fp8(
              av[mf][kk], bv[nf][kk], acc[mf][nf], 0, 0, 0);
    __builtin_amdgcn_s_setprio(0);
    asm volatile("" ::: "memory");
    __builtin_amdgcn_s_barrier();
  }
#undef STAGE

  // epilogue: x = acc/64 + dec; tanh; dot v; 16-col shfl reduce; wn-pair via LDS
  int b = (int)(m0 >> 9);
  int lr = lane >> 4, lc = lane & 15;
  int n0 = bn * 128;
  float dv[4], vv[4];
  #pragma unroll
  for (int nf = 0; nf < 4; nf++) {
    int col = n0 + wn * 64 + nf * 16 + lc;
    dv[nf] = dec[(size_t)b * H_DIM + col];
    vv[nf] = v[col];
  }
  float* epi = (float*)&ldsA[0][0];  // [128 rows][2 wn] floats = 1KB
  #pragma unroll
  for (int mf = 0; mf < 4; mf++) {
    #pragma unroll
    for (int r = 0; r < 4; r++) {
      float s = 0.f;
      #pragma unroll
      for (int nf = 0; nf < 4; nf++) {
        float x = acc[mf][nf][r] * 0.015625f + dv[nf];
        x = fminf(fmaxf(x, -15.f), 15.f);
        float e = __expf(2.f * x);
        s += vv[nf] * (e - 1.f) * __builtin_amdgcn_rcpf(e + 1.f);
      }
      s += __shfl_xor(s, 1); s += __shfl_xor(s, 2);
      s += __shfl_xor(s, 4); s += __shfl_xor(s, 8);
      if (lc == 0) epi[(wm * 64 + mf * 16 + lr * 4 + r) * 2 + wn] = s;
    }
  }
  __syncthreads();
  if (tid < 128) {
    part[(m0 + tid) * 8 + bn] = epi[tid * 2] + epi[tid * 2 + 1];
  }
}

// K4: softmax over T per batch row (8 partials per row)
__global__ void softmax_kernel(const float* __restrict__ part, float* __restrict__ at) {
  int b = blockIdx.x, tid = threadIdx.x;
  __shared__ float sc[512];
  __shared__ float red[8];
  #pragma unroll
  for (int rep = 0; rep < 2; rep++) {
    int t = rep * 256 + tid;
    const float* p = part + ((size_t)b * 512 + t) * 8;
    sc[t] = p[0] + p[1] + p[2] + p[3] + p[4] + p[5] + p[6] + p[7];
  }
  __syncthreads();
  float m = fmaxf(sc[tid], sc[tid + 256]);
  for (int d = 1; d < 64; d <<= 1) m = fmaxf(m, __shfl_xor(m, d));
  if ((tid & 63) == 0) red[tid >> 6] = m;
  __syncthreads();
  m = fmaxf(fmaxf(red[0], red[1]), fmaxf(red[2], red[3]));
  float e0 = __expf(sc[tid] - m), e1 = __expf(sc[tid + 256] - m);
  float s = e0 + e1;
  for (int d = 1; d < 64; d <<= 1) s += __shfl_xor(s, d);
  if ((tid & 63) == 0) red[4 + (tid >> 6)] = s;
  __syncthreads();
  s = red[4] + red[5] + red[6] + red[7];
  float inv = 1.f / s;
  at[(size_t)b * 512 + tid] = e0 * inv;
  at[(size_t)b * 512 + tid + 256] = e1 * inv;
}

// K5: ct_d[b][h] = sum_t at[b][t] * prev[b][t][h] from fp8 frag-major A'
// (values are 4x -> scale 0.25). One wave per (b, kt): in-wave reduction.
__global__ void ctd_ws(const unsigned char* __restrict__ Aq,
                       const float* __restrict__ at, float* __restrict__ out) {
  int wid = blockIdx.x * 4 + (threadIdx.x >> 6);  // 2048 = 64 b x 32 kt
  int lane = threadIdx.x & 63;
  int b = wid >> 5, kt = wid & 31;
  int lc = lane & 15, lr = lane >> 4;
  float a8[8] = {0.f, 0.f, 0.f, 0.f, 0.f, 0.f, 0.f, 0.f};
  const unsigned char* base =
      Aq + ((size_t)b * 32 * 32 + kt) * 512 + (size_t)lane * 8;
  const float* atb = at + (size_t)b * 512;
  #pragma unroll 8
  for (int mt = 0; mt < 32; mt++) {
    float a = atb[mt * 16 + lc];
    uint2 uv = *(const uint2*)(base + (size_t)mt * 16384);
    unsigned char* q = (unsigned char*)&uv;
    #pragma unroll
    for (int j = 0; j < 8; j++) a8[j] += a * e4m3f(q[j]);
  }
  #pragma unroll
  for (int d = 1; d < 16; d <<= 1)
    #pragma unroll
    for (int j = 0; j < 8; j++) a8[j] += __shfl_xor(a8[j], d);
  if (lc == 0) {
    #pragma unroll
    for (int j = 0; j < 8; j++)
      out[(size_t)b * H_DIM + kt * 32 + lr * 8 + j] = a8[j] * 0.25f;
  }
}

extern "C" void kernel_launch(void* const* d_in, const int* in_sizes, int n_in,
                              void* d_out, int out_size, void* d_ws, size_t ws_size,
                              hipStream_t stream) {
  (void)in_sizes; (void)n_in; (void)out_size; (void)ws_size;
  const float* s_t    = (const float*)d_in[0];
  const float* prev_s = (const float*)d_in[1];
  const float* W_prev = (const float*)d_in[2];
  const float* W_s    = (const float*)d_in[3];
  const float* b_s    = (const float*)d_in[4];
  const float* v      = (const float*)d_in[5];
  float* out = (float*)d_out;
  char* ws = (char*)d_ws;

  unsigned char* Aq = (unsigned char*)(ws + AQ8_OFF);
  unsigned char* Bq = (unsigned char*)(ws + BQ8_OFF);
  float* dec  = (float*)(ws + DEC_OFF);
  float* part = (float*)(ws + PART_OFF);
  float* at   = (float*)(ws + AT_OFF);

  prep_ws<<<2128, 256, 0, stream>>>(prev_s, s_t, W_prev, out, Aq, Bq);
  dec_kernel<<<256, 256, 0, stream>>>(s_t, W_s, b_s, dec);
  score_gemm<<<2048, 256, 0, stream>>>(Aq, Bq, dec, v, part);
  softmax_kernel<<<64, 256, 0, stream>>>(part, at);
  ctd_ws<<<512, 256, 0, stream>>>(Aq, at, out);
}